// Round 3
// baseline (668.219 us; speedup 1.0000x reference)
//
#include <hip/hip_runtime.h>
#include <math.h>

#define Bc 8
#define Lc 4096
#define Hc 8
#define Dc 64
#define NCH 8              // equal-WORK chunks (sqrt-spaced causal boundaries)
#define QB 16              // queries per block (4 per wave, one reg-blocked group)
#define VCH 16
#define VROWS (Lc / VCH)   // 256 rows per cumsum chunk

// equal-work causal chunk boundaries: b_c ~= L*(1-sqrt(1-c/8)), 64-aligned
__constant__ int c_cb[NCH + 1] = {0, 256, 576, 832, 1216, 1600, 2048, 2624, 4096};

// ---------------------------------------------------------------- DPP helpers
template<int CTRL>
__device__ __forceinline__ float dpp_mov(float v) {
    return __int_as_float(__builtin_amdgcn_update_dpp(
        0, __float_as_int(v), CTRL, 0xF, 0xF, true));
}
template<int CTRL>
__device__ __forceinline__ float dpp_radd(float v) {
    return v + dpp_mov<CTRL>(v);
}
__device__ __forceinline__ float row16_sum(float p) {
    p = dpp_radd<0x128>(p); p = dpp_radd<0x124>(p);
    p = dpp_radd<0x122>(p); p = dpp_radd<0x121>(p);
    return p;
}
__device__ __forceinline__ float wmax64(float v) {
    v = fmaxf(v, dpp_mov<0x128>(v));
    v = fmaxf(v, dpp_mov<0x124>(v));
    v = fmaxf(v, dpp_mov<0x122>(v));
    v = fmaxf(v, dpp_mov<0x121>(v));
    v = fmaxf(v, __shfl_xor(v, 16, 64));
    return fmaxf(v, __shfl_xor(v, 32, 64));
}
__device__ __forceinline__ float wsum64(float v) {
    v = row16_sum(v);
    v += __shfl_xor(v, 16, 64);
    return v + __shfl_xor(v, 32, 64);
}

// ---------------------------------------------------------------- kernel 1
template<int S>
__global__ __launch_bounds__(256) void k_meas_t(
    const float* __restrict__ Q, const float* __restrict__ K,
    const int* __restrict__ idx, float* __restrict__ M)
{
    constexpr int NIT = (S + 3) / 4;
    int b = blockIdx.z, h = blockIdx.y;
    int w = threadIdx.x >> 6, lane = threadIdx.x & 63;
    int q = blockIdx.x * 4 + w;
    int grp = lane >> 4, gl = lane & 15;

    const float4 qv = *(const float4*)(Q + (((size_t)b * Lc + q) * Hc + h) * Dc + gl * 4);
    const int* ip = idx + (size_t)q * S + grp;
    const float* Kb = K + ((size_t)b * Lc * Hc + h) * Dc + gl * 4;

    int rows[NIT];
    #pragma unroll
    for (int it = 0; it < NIT - 1; it++) rows[it] = ip[it * 4];
    {
        int s = 4 * (NIT - 1) + grp;
        rows[NIT - 1] = ip[(s < S) ? 4 * (NIT - 1) : (S - 1 - grp)];
    }

    float mloc = -INFINITY, sloc = 0.f;
    #pragma unroll
    for (int it = 0; it < NIT; it++) {
        const float4 kw = *(const float4*)(Kb + ((size_t)rows[it] << 9));
        float p = kw.x * qv.x + kw.y * qv.y + kw.z * qv.z + kw.w * qv.w;
        p = row16_sum(p);
        int s = it * 4 + grp;
        if (s < S) { mloc = fmaxf(mloc, p); sloc += p; }
    }
    mloc = fmaxf(mloc, __shfl_xor(mloc, 16, 64));
    mloc = fmaxf(mloc, __shfl_xor(mloc, 32, 64));
    sloc += __shfl_xor(sloc, 16, 64);
    sloc += __shfl_xor(sloc, 32, 64);

    if (lane == 0)
        M[((size_t)(b * Hc + h)) * Lc + q] = mloc - sloc * (1.0f / (float)Lc);
}

__global__ __launch_bounds__(256) void k_meas_dyn(
    const float* __restrict__ Q, const float* __restrict__ K,
    const int* __restrict__ idx, float* __restrict__ M, int S)
{
    int b = blockIdx.z, h = blockIdx.y;
    int w = threadIdx.x >> 6, lane = threadIdx.x & 63;
    int q = blockIdx.x * 4 + w;
    int grp = lane >> 4, gl = lane & 15;

    const float4 qv = *(const float4*)(Q + (((size_t)b * Lc + q) * Hc + h) * Dc + gl * 4);
    const int* ip = idx + (size_t)q * S;
    const float* Kb = K + ((size_t)b * Lc * Hc + h) * Dc + gl * 4;

    float mloc = -INFINITY, sloc = 0.f;
    int niter = (S + 3) >> 2;
    for (int it = 0; it < niter; it++) {
        int s = it * 4 + grp;
        int ii = s < S ? s : S - 1;
        int row = ip[ii];
        const float4 kw = *(const float4*)(Kb + ((size_t)row << 9));
        float p = kw.x * qv.x + kw.y * qv.y + kw.z * qv.z + kw.w * qv.w;
        p = row16_sum(p);
        if (s < S) { mloc = fmaxf(mloc, p); sloc += p; }
    }
    mloc = fmaxf(mloc, __shfl_xor(mloc, 16, 64));
    mloc = fmaxf(mloc, __shfl_xor(mloc, 32, 64));
    sloc += __shfl_xor(sloc, 16, 64);
    sloc += __shfl_xor(sloc, 32, 64);
    if (lane == 0)
        M[((size_t)(b * Hc + h)) * Lc + q] = mloc - sloc * (1.0f / (float)Lc);
}

// ---------------------------------------------------------------- kernel 2
// top-U selection, then sort the selected indices ASCENDING by q so that
// k_attn2 blocks/waves own consecutive order statistics (tight tile cutoffs).
// Order is irrelevant to correctness: reference scatters by row index.
__global__ __launch_bounds__(256) void k_topk(
    const float* __restrict__ M, int* __restrict__ top, int U)
{
    int bh = blockIdx.x;
    int tid = threadIdx.x;
    const float* m = M + (size_t)bh * Lc;

    unsigned long long key[16];
    #pragma unroll
    for (int j = 0; j < 16; j++) {
        int i = tid * 16 + j;
        unsigned int u = __float_as_uint(m[i]);
        u ^= (unsigned int)(((int)u >> 31)) | 0x80000000u;
        key[j] = ((unsigned long long)u << 32) | (unsigned int)i;
    }
    unsigned long long myb = key[0];
    #pragma unroll
    for (int j = 1; j < 16; j++) myb = key[j] > myb ? key[j] : myb;

    __shared__ unsigned long long swave[2][4];
    __shared__ int swin[256];

    for (int u = 0; u < U; u++) {
        unsigned long long wmax = myb;
        #pragma unroll
        for (int o = 32; o >= 1; o >>= 1) {
            unsigned long long t = __shfl_xor(wmax, o, 64);
            wmax = t > wmax ? t : wmax;
        }
        if ((tid & 63) == 0) swave[u & 1][tid >> 6] = wmax;
        __syncthreads();
        unsigned long long w0 = swave[u & 1][0], w1 = swave[u & 1][1];
        unsigned long long w2 = swave[u & 1][2], w3 = swave[u & 1][3];
        unsigned long long a = w0 > w1 ? w0 : w1;
        unsigned long long c = w2 > w3 ? w2 : w3;
        unsigned long long win = a > c ? a : c;
        int widx = (int)(win & 0xFFFFFFFFu);
        if (tid == 0) swin[u] = widx;
        if (tid == (widx >> 4)) {
            #pragma unroll
            for (int j = 0; j < 16; j++) if (j == (widx & 15)) key[j] = 0ull;
            unsigned long long b2 = key[0];
            #pragma unroll
            for (int j = 1; j < 16; j++) b2 = key[j] > b2 ? key[j] : b2;
            myb = b2;
        }
    }
    __syncthreads();
    // odd-even transposition sort ascending (U phases)
    for (int ph = 0; ph < U; ph++) {
        int i = 2 * tid + (ph & 1);
        if (i + 1 < U) {
            int a = swin[i], b2 = swin[i + 1];
            if (a > b2) { swin[i] = b2; swin[i + 1] = a; }
        }
        __syncthreads();
    }
    if (tid < U) top[(size_t)bh * U + tid] = swin[tid];
}

// ---------------------------------------------------------------- kernel 3a
__global__ __launch_bounds__(256) void k_vsum(
    const float* __restrict__ V, float* __restrict__ bsum)
{
    int b = blockIdx.z, h = blockIdx.y, c = blockIdx.x;
    int d = threadIdx.x & 63, g = threadIdx.x >> 6;
    __shared__ float part[4][64];
    float s = 0.f;
    int r0 = c * VROWS;
    for (int r = r0 + g; r < r0 + VROWS; r += 4)
        s += V[(((size_t)b * Lc + r) * Hc + h) * Dc + d];
    part[g][d] = s;
    __syncthreads();
    if (g == 0)
        bsum[(((size_t)(b * Hc + h)) * VCH + c) * 64 + d] =
            part[0][d] + part[1][d] + part[2][d] + part[3][d];
}

// ---------------------------------------------------------------- kernel 3b
__global__ __launch_bounds__(256) void k_scan(
    const float* __restrict__ V, const float* __restrict__ bsum,
    float* __restrict__ out)
{
    int b = blockIdx.z, h = blockIdx.y, c = blockIdx.x;
    int d = threadIdx.x & 63, g = threadIdx.x >> 6;
    int bh = b * Hc + h;
    __shared__ float gtot[4][64];
    __shared__ float goff[4][64];

    float base = 0.f;
    for (int cc = 0; cc < c; cc++)
        base += bsum[((size_t)bh * VCH + cc) * 64 + d];

    int gs = c * VROWS + g * 64;
    float gsum = 0.f;
    for (int r = gs; r < gs + 64; r++)
        gsum += V[(((size_t)b * Lc + r) * Hc + h) * Dc + d];
    gtot[g][d] = gsum;
    __syncthreads();
    if (g == 0) {
        float run = base;
        for (int gg = 0; gg < 4; gg++) { goff[gg][d] = run; run += gtot[gg][d]; }
    }
    __syncthreads();
    float run = goff[g][d];
    for (int r = gs; r < gs + 64; r++) {
        size_t o = (((size_t)b * Lc + r) * Hc + h) * Dc + d;
        run += V[o];
        out[o] = run;
    }
}

// ---------------------------------------------------------------- kernel 4
// flash attention: grid (NCH chunks x QSL query-slices, H, B).
// Block = 16 consecutive sorted queries; wave = 4 consecutive (one group).
// LDS 40KB -> 4 blocks/CU target. K and V tiles XOR-swizzled float4.
__global__ __launch_bounds__(256) void k_attn2(
    const float* __restrict__ Q, const float* __restrict__ K,
    const float* __restrict__ V, const int* __restrict__ top,
    float* __restrict__ Opart, float* __restrict__ Mp, float* __restrict__ Lp,
    int U)
{
    int b = blockIdx.z, h = blockIdx.y;
    int c = blockIdx.x % NCH, s = blockIdx.x / NCH;
    int bh = b * Hc + h;
    int tid = threadIdx.x;
    int lane = tid & 63, g = tid >> 6;

    __shared__ float4 sK4[64][16];   // K row k, phys col = lb ^ (k&7)     16KB
    __shared__ float4 sV4[64][16];   // V^T row d, phys col = kk ^ (d&7)   16KB
    __shared__ float  sQ[QB][64];    //                                      4KB
    __shared__ float  sP[QB][64];    // probs handoff; row0 aliases sqi      4KB

    int* sqi = (int*)&sP[0][0];      // alias: only used before first sP write

    int u0 = s * QB;
    int nu = min(QB, U - u0);
    if (tid < nu) sqi[tid] = top[(size_t)bh * U + u0 + tid];
    __syncthreads();
    for (int u = g; u < nu; u += 4)
        sQ[u][lane] = Q[(((size_t)b * Lc + sqi[u]) * Hc + h) * Dc + lane] * 0.125f;

    int qbm = sqi[nu - 1];           // sorted ascending -> block max q
    int nu1 = nu - 1;
    int l0 = min(4 * g + 0, nu1), l1 = min(4 * g + 1, nu1);
    int l2 = min(4 * g + 2, nu1), l3 = min(4 * g + 3, nu1);
    int q0 = sqi[l0], q1 = sqi[l1], q2 = sqi[l2], q3 = sqi[l3];  // q3 = wave max

    float m0 = -INFINITY, m1 = -INFINITY, m2 = -INFINITY, m3 = -INFINITY;
    float L0 = 0.f, L1 = 0.f, L2 = 0.f, L3 = 0.f;
    float o0 = 0.f, o1 = 0.f, o2 = 0.f, o3 = 0.f;

    int k0c = c_cb[c], k1c = c_cb[c + 1];
    int ntile = 0;
    if (qbm >= k0c) {
        int lastk = min(qbm, k1c - 1);
        ntile = (lastk - k0c) / 64 + 1;
    }
    int kswz = lane & 7;

    for (int t = 0; t < ntile; t++) {
        int k0 = k0c + t * 64;
        __syncthreads();   // previous tile fully consumed (also orders sqi reads)
        {   // stage: thread (row=lane, d-group=g)
            const float* kp = K + (((size_t)b * Lc + k0 + lane) * Hc + h) * Dc + g * 16;
            const float* vp = V + (((size_t)b * Lc + k0 + lane) * Hc + h) * Dc + g * 16;
            #pragma unroll
            for (int i = 0; i < 4; i++) {
                float4 kw = *(const float4*)(kp + i * 4);
                float4 vw = *(const float4*)(vp + i * 4);
                int lb = g * 4 + i;
                sK4[lane][lb ^ kswz] = kw;
                int d0 = lb * 4;
                // V transpose into k-grouped float4s, swizzled per d-row
                ((float*)&sV4[d0 + 0][(lane >> 2) ^ ((d0 + 0) & 7)])[lane & 3] = vw.x;
                ((float*)&sV4[d0 + 1][(lane >> 2) ^ ((d0 + 1) & 7)])[lane & 3] = vw.y;
                ((float*)&sV4[d0 + 2][(lane >> 2) ^ ((d0 + 2) & 7)])[lane & 3] = vw.z;
                ((float*)&sV4[d0 + 3][(lane >> 2) ^ ((d0 + 3) & 7)])[lane & 3] = vw.w;
            }
        }
        __syncthreads();

        if (k0 <= q3) {
            // ---- QK^T: lane = key; 16 swizzled b128 reads shared by 4 queries
            float s0 = 0.f, s1 = 0.f, s2 = 0.f, s3 = 0.f;
            #pragma unroll
            for (int lb = 0; lb < 16; lb++) {
                float4 kb = sK4[lane][lb ^ kswz];
                float4 qa = *(const float4*)&sQ[l0][lb * 4];
                float4 qb = *(const float4*)&sQ[l1][lb * 4];
                float4 qc = *(const float4*)&sQ[l2][lb * 4];
                float4 qd = *(const float4*)&sQ[l3][lb * 4];
                s0 += kb.x*qa.x + kb.y*qa.y + kb.z*qa.z + kb.w*qa.w;
                s1 += kb.x*qb.x + kb.y*qb.y + kb.z*qb.z + kb.w*qb.w;
                s2 += kb.x*qc.x + kb.y*qc.y + kb.z*qc.z + kb.w*qc.w;
                s3 += kb.x*qd.x + kb.y*qd.y + kb.z*qd.z + kb.w*qd.w;
            }
            // ---- online softmax (4 independent chains)
            float a0, a1, a2, a3;
#define SLOT(li, qi, sv, mv, lv, av) { \
            float sA = (k0 + lane > qi) ? -INFINITY : sv; \
            float tm = wmax64(sA); \
            float mnew = fmaxf(mv, tm); \
            float p = __expf(sA - mnew); \
            float ps = wsum64(p); \
            av = __expf(mv - mnew); \
            mv = mnew; \
            lv = lv * av + ps; \
            sP[li][lane] = p; }
            SLOT(l0, q0, s0, m0, L0, a0)
            SLOT(l1, q1, s1, m1, L1, a1)
            SLOT(l2, q2, s2, m2, L2, a2)
            SLOT(l3, q3, s3, m3, L3, a3)
#undef SLOT
            // ---- PV: lane = d; 16 swizzled b128 V reads shared by 4 queries
            float p0 = 0.f, p1 = 0.f, p2 = 0.f, p3 = 0.f;
            #pragma unroll
            for (int kk = 0; kk < 16; kk++) {
                float4 vb = sV4[lane][kk ^ kswz];
                float4 wa = *(const float4*)&sP[l0][kk * 4];
                float4 wb = *(const float4*)&sP[l1][kk * 4];
                float4 wc = *(const float4*)&sP[l2][kk * 4];
                float4 wd = *(const float4*)&sP[l3][kk * 4];
                p0 += wa.x*vb.x + wa.y*vb.y + wa.z*vb.z + wa.w*vb.w;
                p1 += wb.x*vb.x + wb.y*vb.y + wb.z*vb.z + wb.w*vb.w;
                p2 += wc.x*vb.x + wc.y*vb.y + wc.z*vb.z + wc.w*vb.w;
                p3 += wd.x*vb.x + wd.y*vb.y + wd.z*vb.z + wd.w*vb.w;
            }
            o0 = o0 * a0 + p0;
            o1 = o1 * a1 + p1;
            o2 = o2 * a2 + p2;
            o3 = o3 * a3 + p3;
        }
    }

    // always write partials (even ntile==0): combine's lv>0 guard needs them.
    // duplicate slots write identical values to identical addresses (safe).
#define WR(li, mv, lv, ov) { \
    size_t s0_ = ((size_t)bh * NCH + c) * U + (u0 + li); \
    Opart[s0_ * 64 + lane] = ov; \
    if (lane == 0) { Mp[s0_] = mv; Lp[s0_] = lv; } }
    WR(l0, m0, L0, o0)
    WR(l1, m1, L1, o1)
    WR(l2, m2, L2, o2)
    WR(l3, m3, L3, o3)
#undef WR
}

// ---------------------------------------------------------------- kernel 5
__global__ __launch_bounds__(64) void k_combine(
    const float* __restrict__ Opart, const float* __restrict__ Mp,
    const float* __restrict__ Lp, const int* __restrict__ top,
    float* __restrict__ out, int U)
{
    int b = blockIdx.z, h = blockIdx.y, u = blockIdx.x;
    int bh = b * Hc + h;
    int lane = threadIdx.x;
    int q = top[(size_t)bh * U + u];

    float mv[NCH], lv[NCH];
    float mg = -INFINITY;
    #pragma unroll
    for (int c = 0; c < NCH; c++) {
        size_t s0 = ((size_t)bh * NCH + c) * U + u;
        mv[c] = Mp[s0]; lv[c] = Lp[s0];
        mg = fmaxf(mg, mv[c]);
    }
    float Ls = 0.f, o = 0.f;
    #pragma unroll
    for (int c = 0; c < NCH; c++) {
        if (lv[c] > 0.f) {
            float w = __expf(mv[c] - mg);
            Ls += w * lv[c];
            o  += w * Opart[(((size_t)bh * NCH + c) * U + u) * 64 + lane];
        }
    }
    out[(((size_t)b * Lc + q) * Hc + h) * Dc + lane] = o / Ls;
}

extern "C" void kernel_launch(void* const* d_in, const int* in_sizes, int n_in,
                              void* d_out, int out_size, void* d_ws, size_t ws_size,
                              hipStream_t stream)
{
    const float* Q = (const float*)d_in[0];
    const float* K = (const float*)d_in[1];
    const float* V = (const float*)d_in[2];
    const int* idx = (const int*)d_in[3];
    float* out = (float*)d_out;

    int S = in_sizes[3] / Lc;   // sample_k == u == 45
    int QSL = (S + QB - 1) / QB;

    char* ws = (char*)d_ws;
    float* M     = (float*)ws;                          // 1 MB
    float* Opart = (float*)ws;                          // 5.90 MB (overlaps M)
    float* Mp    = (float*)(ws + 6291456);              // 90 KB
    float* Lp    = (float*)(ws + 6422528);              // 90 KB
    float* bsum  = (float*)(ws + 6815744);              // 256 KB
    int*   top   = (int*)  (ws + 8388608);              // 11.5 KB

    dim3 blk(256);
    if (S == 45)
        k_meas_t<45><<<dim3(Lc / 4, Hc, Bc), blk, 0, stream>>>(Q, K, idx, M);
    else
        k_meas_dyn  <<<dim3(Lc / 4, Hc, Bc), blk, 0, stream>>>(Q, K, idx, M, S);
    k_topk   <<<dim3(Bc * Hc),          blk, 0, stream>>>(M, top, S);
    k_vsum   <<<dim3(VCH, Hc, Bc),      blk, 0, stream>>>(V, bsum);
    k_scan   <<<dim3(VCH, Hc, Bc),      blk, 0, stream>>>(V, bsum, out);
    k_attn2  <<<dim3(NCH * QSL, Hc, Bc), blk, 0, stream>>>(Q, K, V, top, Opart, Mp, Lp, S);
    k_combine<<<dim3(S, Hc, Bc), dim3(64), 0, stream>>>(Opart, Mp, Lp, top, out, S);
}